// Round 1
// baseline (6009.100 us; speedup 1.0000x reference)
//
#include <hip/hip_runtime.h>
#include <hip/hip_fp16.h>

typedef _Float16 f16;
typedef _Float16 f16x8 __attribute__((ext_vector_type(8)));
typedef float f32x4 __attribute__((ext_vector_type(4)));

#define DI static __device__ __forceinline__

constexpr int N2 = 257 * 257;
#define LSTRIDE ((size_t)254 * 32 * 768)

DI f32x4 mfma16(f16x8 a, f16x8 b, f32x4 c) {
  return __builtin_amdgcn_mfma_f32_16x16x32_f16(a, b, c, 0, 0, 0);
}
DI f16x8 ldg8(const f16* p) { return *reinterpret_cast<const f16x8*>(p); }
DI f16x8 cvt8(const float* s) {
  f16x8 v;
#pragma unroll
  for (int j = 0; j < 8; ++j) v[j] = (f16)s[j];
  return v;
}
DI double invfact(int k) {
  double f = 1.0;
  for (int i = 2; i <= k; ++i) f *= (double)i;
  return 1.0 / f;
}

DI void gridbar(int* bar, int nwg) {
  __syncthreads();
  if (threadIdx.x == 0) {
    __builtin_amdgcn_fence(__ATOMIC_RELEASE, "agent");
    int g = __hip_atomic_load(bar + 1, __ATOMIC_RELAXED, __HIP_MEMORY_SCOPE_AGENT);
    int old = __hip_atomic_fetch_add(bar, 1, __ATOMIC_RELAXED, __HIP_MEMORY_SCOPE_AGENT);
    if (old == nwg - 1) {
      __hip_atomic_store(bar, 0, __ATOMIC_RELAXED, __HIP_MEMORY_SCOPE_AGENT);
      __hip_atomic_fetch_add(bar + 1, 1, __ATOMIC_RELEASE, __HIP_MEMORY_SCOPE_AGENT);
    } else {
      while (__hip_atomic_load(bar + 1, __ATOMIC_RELAXED, __HIP_MEMORY_SCOPE_AGENT) == g)
        __builtin_amdgcn_s_sleep(1);
    }
    __builtin_amdgcn_fence(__ATOMIC_ACQUIRE, "agent");
  }
  __syncthreads();
}

// D = A*B (257x257 double), optionally fused += c0*I + c1*T1 + c2*T2 + c3*T3 (Taylor block)
DI void mm257(double* __restrict__ D, const double* __restrict__ A, const double* __restrict__ Bm,
              int fj, const double* __restrict__ T1, const double* __restrict__ T2,
              const double* __restrict__ T3, int gtid, int nth) {
  double c0 = 0, c1 = 0, c2 = 0, c3 = 0;
  if (fj >= 0) {
    c0 = invfact(4 * fj); c1 = invfact(4 * fj + 1);
    c2 = invfact(4 * fj + 2); c3 = invfact(4 * fj + 3);
  }
  for (int e = gtid; e < N2; e += nth) {
    int i = e / 257, j = e - i * 257;
    const double* ar = A + (size_t)i * 257;
    const double* bc = Bm + j;
    double s = 0.0;
    for (int k = 0; k < 257; ++k) s = fma(ar[k], bc[(size_t)k * 257], s);
    if (fj >= 0) s += c0 * ((i == j) ? 1.0 : 0.0) + c1 * T1[e] + c2 * T2[e] + c3 * T3[e];
    D[e] = s;
  }
}

// ---------------- K1: expm + all precomputation ----------------
__global__ __launch_bounds__(256) void k_setup(
    const float* __restrict__ dayW, const float* __restrict__ ex0, const float* __restrict__ Wx0,
    const float* __restrict__ exr, const float* __restrict__ Wxr,
    const float* __restrict__ eh, const float* __restrict__ em,
    const float* __restrict__ Wh, const float* __restrict__ Wm,
    const float* __restrict__ h0, const float* __restrict__ m0, const float* __restrict__ outW,
    double* __restrict__ X, float* __restrict__ w1f, float* __restrict__ AWt,
    float* __restrict__ btf, f16* __restrict__ gbuf, f16* __restrict__ wxcat,
    f16* __restrict__ outw, f16* __restrict__ dayWt, f16* __restrict__ sbuf,
    int* __restrict__ bar) {
  const int gtid = blockIdx.x * 256 + threadIdx.x;
  const int nth = 64 * 256;
  double* Ms = X;
  double* M2 = X + N2;
  double* M3 = X + 2 * N2;
  double* M4 = X + 3 * N2;
  double* Xa = X + 4 * N2;
  double* Xb = X + 5 * N2;

  // ---- phase 0: fills + scaled augmented matrix ----
  for (int e = gtid; e < N2; e += nth) {
    int i = e / 257, j = e - i * 257;
    double v = 0.0;
    if (i < 256) {
      double R = (2.0 * i + 1.0) / 256.0;
      if (j < 256) v = R * ((i < j) ? -1.0 : (((i - j) & 1) ? 1.0 : -1.0));
      else v = R * ((i & 1) ? -1.0 : 1.0);
    }
    Ms[e] = v / 64.0;  // s = 6
  }
  for (int e = gtid; e < 576 * 896; e += nth) {  // wxcat [576][7168] = [Wx0 | ex0 | 0]
    int n = e / 896, kc = (e - n * 896) * 8;
    f16x8 v;
    if (n < 512) v = cvt8(Wx0 + (size_t)n * 7168 + kc);
    else if (n == 512) v = cvt8(ex0 + kc);
    else {
#pragma unroll
      for (int j = 0; j < 8; ++j) v[j] = (f16)0.f;
    }
    *reinterpret_cast<f16x8*>(wxcat + (size_t)n * 7168 + kc) = v;
  }
  for (int e = gtid; e < 48 * 64; e += nth) {  // outw [48][512]
    int n = e / 64, kc = (e - n * 64) * 8;
    f16x8 v;
    if (n < 41) v = cvt8(outW + (size_t)n * 512 + kc);
    else {
#pragma unroll
      for (int j = 0; j < 8; ++j) v[j] = (f16)0.f;
    }
    *reinterpret_cast<f16x8*>(outw + (size_t)n * 512 + kc) = v;
  }
  for (int e = gtid; e < 5 * 32 * 96; e += nth) {  // sbuf tau=0 init
    int l = e / (32 * 96); int r = e - l * 32 * 96; int b = r / 96; int kc = (r - b * 96) * 8;
    f16x8 v = (kc < 512) ? cvt8(h0 + (size_t)l * 512 + kc) : cvt8(m0 + (size_t)l * 256 + (kc - 512));
    *reinterpret_cast<f16x8*>(sbuf + (size_t)l * LSTRIDE + (size_t)b * 768 + kc) = v;
  }
  {  // dayWt[D][n][k] = dayW[D][k][n] via LDS tile transpose
    __shared__ float tile[64][65];
    for (int tt = blockIdx.x; tt < 24 * 64; tt += 64) {
      int D = tt >> 6; int r = tt & 63; int kb = (r >> 3) * 64; int nb = (r & 7) * 64;
      __syncthreads();
      for (int q = 0; q < 16; ++q) {
        int idx = threadIdx.x + q * 256; int kk = idx >> 6; int nn = idx & 63;
        tile[kk][nn] = dayW[(size_t)D * 262144 + (size_t)(kb + kk) * 512 + nb + nn];
      }
      __syncthreads();
      for (int q = 0; q < 2; ++q) {
        int cidx = threadIdx.x + q * 256; int nn = cidx >> 3; int kc = (cidx & 7) * 8;
        f16x8 v;
#pragma unroll
        for (int jj = 0; jj < 8; ++jj) v[jj] = (f16)tile[kc + jj][nn];
        *reinterpret_cast<f16x8*>(dayWt + (size_t)D * 262144 + (size_t)(nb + nn) * 512 + kb + kc) = v;
      }
    }
    __syncthreads();
  }
  gridbar(bar, 64);

  // ---- expm: powers, PS-Horner (deg 24), 6 squarings ----
  mm257(M2, Ms, Ms, -1, Ms, Ms, Ms, gtid, nth); gridbar(bar, 64);
  mm257(M3, M2, Ms, -1, Ms, Ms, Ms, gtid, nth); gridbar(bar, 64);
  mm257(M4, M2, M2, -1, Ms, Ms, Ms, gtid, nth);
  for (int e = gtid; e < N2; e += nth) {  // B6 = c24*I
    int i = e / 257, j = e - i * 257;
    Xa[e] = (i == j) ? invfact(24) : 0.0;
  }
  gridbar(bar, 64);
  double* src = Xa; double* dst = Xb;
  for (int j5 = 5; j5 >= 0; --j5) {
    mm257(dst, src, M4, j5, Ms, M2, M3, gtid, nth);
    gridbar(bar, 64);
    double* tmp = src; src = dst; dst = tmp;
  }
  for (int q = 0; q < 6; ++q) {
    mm257(dst, src, src, -1, Ms, Ms, Ms, gtid, nth);
    gridbar(bar, 64);
    double* tmp = src; src = dst; dst = tmp;
  }
  const double* E = src;  // exp(aug): A = E[:256,:256], bt = E[:256,256]

  // ---- bt, w1, AWt ----
  for (int e = gtid; e < 256; e += nth) btf[e] = (float)E[(size_t)e * 257 + 256];
  for (int e = gtid; e < 5 * 512; e += nth) {
    int l = e / 512, n = e - l * 512;
    float s = 0.f;
    for (int j = 0; j < 256; ++j)
      s += (float)E[(size_t)j * 257 + 256] * Wm[((size_t)l * 512 + n) * 256 + j];
    w1f[e] = s;
  }
  for (int e = gtid; e < 5 * 512 * 256; e += nth) {
    int l = e / (512 * 256); int r = e - l * 512 * 256; int n = r >> 8; int i = r & 255;
    float s = 0.f;
    for (int j = 0; j < 256; ++j)
      s += (float)E[(size_t)j * 257 + i] * Wm[((size_t)l * 512 + n) * 256 + j];
    AWt[e] = s;
  }
  gridbar(bar, 64);

  // ---- gbuf[l][n][k] fill (n-major, k in [h(512)|m(256)|x(512)]) ----
  for (int e = gtid; e < 5 * 768 * 160; e += nth) {
    int l = e / (768 * 160); int r = e - l * 768 * 160; int n = r / 160; int k = (r - n * 160) * 8;
    if (l == 0 && k >= 768) continue;
    f16x8 v;
    if (n < 512) {
      float w1n = w1f[l * 512 + n];
      if (k < 512) {
        const float* a = Wh + ((size_t)l * 512 + n) * 512 + k;
        const float* b = eh + (size_t)l * 512 + k;
#pragma unroll
        for (int jj = 0; jj < 8; ++jj) v[jj] = (f16)(a[jj] + b[jj] * w1n);
      } else if (k < 768) {
        int i = k - 512;
        const float* a = AWt + ((size_t)l * 512 + n) * 256 + i;
        const float* b = em + (size_t)l * 256 + i;
#pragma unroll
        for (int jj = 0; jj < 8; ++jj) v[jj] = (f16)(a[jj] + b[jj] * w1n);
      } else {
        int d = k - 768;
        const float* a = Wxr + ((size_t)(l - 1) * 512 + n) * 512 + d;
        const float* b = exr + (size_t)(l - 1) * 512 + d;
#pragma unroll
        for (int jj = 0; jj < 8; ++jj) v[jj] = (f16)(a[jj] + b[jj] * w1n);
      }
    } else {
      int jm = n - 512;
      float btn = btf[jm];
      if (k < 512) {
        const float* b = eh + (size_t)l * 512 + k;
#pragma unroll
        for (int jj = 0; jj < 8; ++jj) v[jj] = (f16)(b[jj] * btn);
      } else if (k < 768) {
        int i = k - 512;
        const double* a = E + (size_t)jm * 257 + i;
        const float* b = em + (size_t)l * 256 + i;
#pragma unroll
        for (int jj = 0; jj < 8; ++jj) v[jj] = (f16)((float)a[jj] + b[jj] * btn);
      } else {
        int d = k - 768;
        const float* b = exr + (size_t)(l - 1) * 512 + d;
#pragma unroll
        for (int jj = 0; jj < 8; ++jj) v[jj] = (f16)(b[jj] * btn);
      }
    }
    *reinterpret_cast<f16x8*>(gbuf + ((size_t)l * 768 + n) * 1280 + k) = v;
  }
}

// ---------------- K2: day-specific linear + softsign -> h1 (f16) ----------------
__global__ __launch_bounds__(256) void k_day(const float* __restrict__ x,
    const int* __restrict__ dayIdx, const float* __restrict__ dayb,
    const f16* __restrict__ dayWt, f16* __restrict__ h1) {
  __shared__ f16 As[64][40];
  __shared__ f16 Bs[256][40];
  const int bid = blockIdx.x;
  const int b = bid >> 5; const int r = bid & 31;
  const int t0 = (r >> 1) * 64; const int n0 = (r & 1) * 256;
  const int D = dayIdx[b];
  const int tid = threadIdx.x, lane = tid & 63, w = tid >> 6, q4 = lane >> 4;
  const float* xb = x + ((size_t)b * 1024 + t0) * 512;
  const f16* Wt = dayWt + (size_t)D * 262144 + (size_t)n0 * 512;
  f32x4 acc[16];
#pragma unroll
  for (int i = 0; i < 16; ++i) acc[i] = (f32x4){0.f, 0.f, 0.f, 0.f};
  for (int kt = 0; kt < 16; ++kt) {
    const int k0 = kt * 32;
    __syncthreads();
    { int row = tid >> 2, c8 = (tid & 3) * 8;
      *reinterpret_cast<f16x8*>(&As[row][c8]) = cvt8(xb + (size_t)row * 512 + k0 + c8); }
    for (int q = 0; q < 4; ++q) {
      int idx = tid + q * 256; int row = idx >> 2; int c8 = (idx & 3) * 8;
      *reinterpret_cast<f16x8*>(&Bs[row][c8]) = ldg8(Wt + (size_t)row * 512 + k0 + c8);
    }
    __syncthreads();
    f16x8 a = *reinterpret_cast<const f16x8*>(&As[w * 16 + (lane & 15)][q4 * 8]);
#pragma unroll
    for (int nt2 = 0; nt2 < 16; ++nt2) {
      f16x8 bb = *reinterpret_cast<const f16x8*>(&Bs[nt2 * 16 + (lane & 15)][q4 * 8]);
      acc[nt2] = mfma16(a, bb, acc[nt2]);
    }
  }
#pragma unroll
  for (int nt2 = 0; nt2 < 16; ++nt2) {
    int n = n0 + nt2 * 16 + (lane & 15);
    float db = dayb[(size_t)D * 512 + n];
#pragma unroll
    for (int i = 0; i < 4; ++i) {
      int t = t0 + w * 16 + q4 * 4 + i;
      float v = acc[nt2][i] + db;
      v = v / (1.f + fabsf(v));
      h1[((size_t)b * 1024 + t) * 512 + n] = (f16)v;
    }
  }
}

// ---------------- K3: layer-0 input GEMM (patch-gathered) -> xw0 [8192][576] f32 ----------------
__global__ __launch_bounds__(256) void k_xw0(const f16* __restrict__ h1,
    const f16* __restrict__ wxcat, float* __restrict__ xw0) {
  __shared__ f16 As[128][40];
  __shared__ f16 Bs[192][40];
  const int bid = blockIdx.x;
  const int mt = bid / 3; const int nb = bid - mt * 3;
  const int m0 = mt * 128; const int n0 = nb * 192;
  const int tid = threadIdx.x, lane = tid & 63, w = tid >> 6, q4 = lane >> 4;
  f32x4 acc[2][12];
#pragma unroll
  for (int a = 0; a < 2; ++a)
#pragma unroll
    for (int b = 0; b < 12; ++b) acc[a][b] = (f32x4){0.f, 0.f, 0.f, 0.f};
  for (int kt = 0; kt < 224; ++kt) {
    const int k0 = kt * 32; const int p = k0 >> 9; const int kd = k0 & 511;
    __syncthreads();
    for (int q = 0; q < 2; ++q) {
      int idx = tid + q * 256; int row = idx >> 2; int c8 = (idx & 3) * 8;
      int m = m0 + row; int b = m >> 8; int tp = m & 255; if (tp > 252) tp = 252;
      *reinterpret_cast<f16x8*>(&As[row][c8]) =
          ldg8(h1 + ((size_t)b * 1024 + (size_t)tp * 4 + p) * 512 + kd + c8);
    }
    for (int q = 0; q < 3; ++q) {
      int idx = tid + q * 256; int row = idx >> 2; int c8 = (idx & 3) * 8;
      *reinterpret_cast<f16x8*>(&Bs[row][c8]) =
          ldg8(wxcat + (size_t)(n0 + row) * 7168 + k0 + c8);
    }
    __syncthreads();
#pragma unroll
    for (int mb = 0; mb < 2; ++mb) {
      f16x8 a = *reinterpret_cast<const f16x8*>(&As[w * 32 + mb * 16 + (lane & 15)][q4 * 8]);
#pragma unroll
      for (int nt2 = 0; nt2 < 12; ++nt2) {
        f16x8 bb = *reinterpret_cast<const f16x8*>(&Bs[nt2 * 16 + (lane & 15)][q4 * 8]);
        acc[mb][nt2] = mfma16(a, bb, acc[mb][nt2]);
      }
    }
  }
#pragma unroll
  for (int mb = 0; mb < 2; ++mb)
#pragma unroll
    for (int nt2 = 0; nt2 < 12; ++nt2)
#pragma unroll
      for (int i = 0; i < 4; ++i) {
        int m = m0 + w * 32 + mb * 16 + q4 * 4 + i;
        int n = n0 + nt2 * 16 + (lane & 15);
        xw0[(size_t)m * 576 + n] = acc[mb][nt2][i];
      }
}

// ---------------- K4: pipelined LMU recurrence ----------------
template <int KK>
DI void rec_run(int l, int c, int tid, const f16* __restrict__ gbuf, f16* __restrict__ sbuf,
                const float* __restrict__ xw0, const float* __restrict__ w1f,
                const float* __restrict__ btf, int* __restrict__ done, f16* bflds) {
  const int lane = tid & 63, w = tid >> 6;
  const int mb = w / 3, nt = w % 3;
  const int nbase = c * 48 + nt * 16;
  const int ncol = nbase + (lane & 15);
  const int q4 = lane >> 4;

  const f16* gb = gbuf + ((size_t)l * 768 + ncol) * 1280 + (size_t)q4 * 8;
  constexpr int NREG = (KK > 32) ? 32 : KK;
  f16x8 bf[NREG];
#pragma unroll
  for (int kk = 0; kk < NREG; ++kk) bf[kk] = ldg8(gb + (size_t)kk * 32);
  if (KK == 40) {
#pragma unroll
    for (int kk = 32; kk < 40; ++kk) {
      f16x8 v = ldg8(gb + (size_t)kk * 32);
      *reinterpret_cast<f16x8*>(bflds + ((size_t)(w * 8 + (kk - 32)) * 64 + lane) * 8) = v;
    }
  }
  __syncthreads();

  float w1n = 0.f, btn = 0.f;
  if (KK == 24) {
    if (ncol < 512) w1n = w1f[ncol];
    else btn = btf[ncol - 512];
  }

  for (int t = 0; t < 253; ++t) {
    if (tid == 0) {
      if (t > 0)
        while (__hip_atomic_load(done + l * 256 + t, __ATOMIC_RELAXED, __HIP_MEMORY_SCOPE_AGENT) < 16)
          __builtin_amdgcn_s_sleep(1);
      if (l > 0)
        while (__hip_atomic_load(done + (l - 1) * 256 + t + 1, __ATOMIC_RELAXED, __HIP_MEMORY_SCOPE_AGENT) < 16)
          __builtin_amdgcn_s_sleep(1);
      __builtin_amdgcn_fence(__ATOMIC_ACQUIRE, "agent");
    }
    __syncthreads();

    const int arow = mb * 16 + (lane & 15);
    const f16* s0 = sbuf + (size_t)l * LSTRIDE + ((size_t)t * 32 + arow) * 768 + (size_t)q4 * 8;
    f32x4 acc = {0.f, 0.f, 0.f, 0.f};
#pragma unroll
    for (int kk = 0; kk < 24; ++kk) acc = mfma16(ldg8(s0 + (size_t)kk * 32), bf[kk < NREG ? kk : 0], acc);
    if (KK == 40) {
      const f16* s1 = sbuf + (size_t)(l - 1) * LSTRIDE + ((size_t)(t + 1) * 32 + arow) * 768 + (size_t)q4 * 8;
#pragma unroll
      for (int kk = 24; kk < 32; ++kk) acc = mfma16(ldg8(s1 + (size_t)(kk - 24) * 32), bf[kk < NREG ? kk : 0], acc);
#pragma unroll
      for (int kk = 32; kk < 40; ++kk) {
        f16x8 bb = *reinterpret_cast<const f16x8*>(bflds + ((size_t)(w * 8 + (kk - 32)) * 64 + lane) * 8);
        acc = mfma16(ldg8(s1 + (size_t)(kk - 24) * 32), bb, acc);
      }
    }

    f16* dst = sbuf + (size_t)l * LSTRIDE + ((size_t)(t + 1) * 32) * 768;
#pragma unroll
    for (int i = 0; i < 4; ++i) {
      const int brow = mb * 16 + q4 * 4 + i;
      float v = acc[i];
      if (KK == 24) {
        const float* xr = xw0 + ((size_t)brow * 256 + t) * 576;
        float xe = xr[512];
        v += (ncol < 512) ? (xr[ncol] + xe * w1n) : (xe * btn);
      }
      if (ncol < 512) v = tanhf(v);
      dst[(size_t)brow * 768 + ncol] = (f16)v;
    }
    __syncthreads();
    if (tid == 0) {
      __builtin_amdgcn_fence(__ATOMIC_RELEASE, "agent");
      __hip_atomic_fetch_add(done + l * 256 + t + 1, 1, __ATOMIC_RELAXED, __HIP_MEMORY_SCOPE_AGENT);
    }
  }
}

__global__ __launch_bounds__(384, 2) void k_rec(const f16* __restrict__ gbuf, f16* __restrict__ sbuf,
    const float* __restrict__ xw0, const float* __restrict__ w1f,
    const float* __restrict__ btf, int* __restrict__ done) {
  __shared__ f16 bflds[6 * 8 * 64 * 8];
  const int l = blockIdx.x & 7;
  if (l >= 5) return;
  const int c = blockIdx.x >> 3;
  if (l == 0)
    rec_run<24>(0, c, threadIdx.x, gbuf, sbuf, xw0, w1f, btf, done, bflds);
  else
    rec_run<40>(l, c, threadIdx.x, gbuf, sbuf, xw0, w1f, btf, done, bflds);
}

// ---------------- K5: output projection ----------------
__global__ __launch_bounds__(256) void k_out(const f16* __restrict__ sbuf4,
    const f16* __restrict__ outw, const float* __restrict__ outb, float* __restrict__ out) {
  const int bid = blockIdx.x; const int b = bid >> 2; const int tp0 = (bid & 3) * 64;
  const int tid = threadIdx.x, lane = tid & 63, w = tid >> 6, q4 = lane >> 4;
  f32x4 acc[3];
#pragma unroll
  for (int i = 0; i < 3; ++i) acc[i] = (f32x4){0.f, 0.f, 0.f, 0.f};
  int tq = tp0 + w * 16 + (lane & 15) + 1;
  const int tau = tq > 253 ? 253 : tq;
  const f16* arow = sbuf4 + ((size_t)tau * 32 + b) * 768 + (size_t)q4 * 8;
#pragma unroll
  for (int kk = 0; kk < 16; ++kk) {
    f16x8 a = ldg8(arow + (size_t)kk * 32);
#pragma unroll
    for (int nt2 = 0; nt2 < 3; ++nt2) {
      f16x8 bb = ldg8(outw + (size_t)(nt2 * 16 + (lane & 15)) * 512 + kk * 32 + q4 * 8);
      acc[nt2] = mfma16(a, bb, acc[nt2]);
    }
  }
#pragma unroll
  for (int nt2 = 0; nt2 < 3; ++nt2) {
    int cc = nt2 * 16 + (lane & 15);
    if (cc < 41) {
      float ob = outb[cc];
#pragma unroll
      for (int i = 0; i < 4; ++i) {
        int tp = tp0 + w * 16 + q4 * 4 + i;
        if (tp < 253) out[((size_t)b * 253 + tp) * 41 + cc] = acc[nt2][i] + ob;
      }
    }
  }
}

extern "C" void kernel_launch(void* const* d_in, const int* in_sizes, int n_in,
                              void* d_out, int out_size, void* d_ws, size_t ws_size,
                              hipStream_t stream) {
  const float* x      = (const float*)d_in[0];
  const int*   dayIdx = (const int*)d_in[1];
  const float* day_W  = (const float*)d_in[2];
  const float* day_b  = (const float*)d_in[3];
  const float* e_x0   = (const float*)d_in[4];
  const float* W_x0   = (const float*)d_in[5];
  const float* e_xr   = (const float*)d_in[6];
  const float* W_xr   = (const float*)d_in[7];
  const float* e_h    = (const float*)d_in[8];
  const float* e_m    = (const float*)d_in[9];
  const float* W_h    = (const float*)d_in[10];
  const float* W_m    = (const float*)d_in[11];
  const float* h0     = (const float*)d_in[12];
  const float* m0     = (const float*)d_in[13];
  const float* out_W  = (const float*)d_in[14];
  const float* out_b  = (const float*)d_in[15];
  float* outp = (float*)d_out;

  char* w = (char*)d_ws;
  size_t o = 0;
  auto al = [&](size_t n) { void* p = w + o; o = (o + n + 255) & ~(size_t)255; return p; };
  int*    flags = (int*)   al(8192);
  double* X     = (double*)al((size_t)6 * N2 * 8);
  float*  w1f   = (float*) al((size_t)5 * 512 * 4);
  float*  AWt   = (float*) al((size_t)5 * 512 * 256 * 4);
  float*  btf   = (float*) al(256 * 4);
  f16*    gbuf  = (f16*)   al((size_t)5 * 768 * 1280 * 2);
  f16*    wxcat = (f16*)   al((size_t)576 * 7168 * 2);
  f16*    outw  = (f16*)   al((size_t)48 * 512 * 2);
  f16*    dayWt = (f16*)   al((size_t)24 * 512 * 512 * 2);
  f16*    h1    = (f16*)   al((size_t)32 * 1024 * 512 * 2);
  float*  xw0   = (float*) al((size_t)8192 * 576 * 4);
  f16*    sbuf  = (f16*)   al((size_t)5 * LSTRIDE * 2);
  if (o > ws_size) return;  // workspace too small -> fail loudly (output stays poisoned)
  int* bar = flags + 5 * 256;
  (void)bar; (void)in_sizes; (void)n_in; (void)out_size;

  hipMemsetAsync(flags, 0, 8192, stream);
  k_setup<<<64, 256, 0, stream>>>(day_W, e_x0, W_x0, e_xr, W_xr, e_h, e_m, W_h, W_m,
                                  h0, m0, out_W, X, w1f, AWt, btf, gbuf, wxcat, outw,
                                  dayWt, sbuf, flags + 5 * 256);
  k_day<<<1024, 256, 0, stream>>>(x, dayIdx, day_b, dayWt, h1);
  k_xw0<<<192, 256, 0, stream>>>(h1, wxcat, xw0);
  k_rec<<<128, 384, 0, stream>>>(gbuf, sbuf, xw0, w1f, btf, flags);
  k_out<<<128, 256, 0, stream>>>(sbuf + (size_t)4 * LSTRIDE, outw, out_b, outp);
}

// Round 4
// 4251.654 us; speedup vs baseline: 1.4134x; 1.4134x over previous
//
#include <hip/hip_runtime.h>
#include <hip/hip_fp16.h>

typedef _Float16 f16;
typedef _Float16 f16x8 __attribute__((ext_vector_type(8)));
typedef float f32x4 __attribute__((ext_vector_type(4)));

#define DI static __device__ __forceinline__

constexpr int N2 = 257 * 257;
#define LSTRIDE ((size_t)254 * 32 * 768)

DI f32x4 mfma16(f16x8 a, f16x8 b, f32x4 c) {
  return __builtin_amdgcn_mfma_f32_16x16x32_f16(a, b, c, 0, 0, 0);
}
DI f16x8 ldg8(const f16* p) { return *reinterpret_cast<const f16x8*>(p); }
DI f16x8 cvt8(const float* s) {
  f16x8 v;
#pragma unroll
  for (int j = 0; j < 8; ++j) v[j] = (f16)s[j];
  return v;
}
DI double invfact(int k) {
  double f = 1.0;
  for (int i = 2; i <= k; ++i) f *= (double)i;
  return 1.0 / f;
}

// ---- visibility helpers: sc1 = write-through to LLC; flags via LLC atomics ----
DI void st_d_sc1(double* p, double v) {
  asm volatile("global_store_dwordx2 %0, %1, off sc1" :: "v"(p), "v"(v) : "memory");
}
DI void st_f_sc1(float* p, float v) {
  asm volatile("global_store_dword %0, %1, off sc1" :: "v"(p), "v"(v) : "memory");
}
DI void st_h_sc1(f16* p, f16 v) {
  asm volatile("global_store_short %0, %1, off sc1" :: "v"(p), "v"(v) : "memory");
}
DI int ld_llc(const int* p) {
  return __hip_atomic_load(p, __ATOMIC_RELAXED, __HIP_MEMORY_SCOPE_AGENT);
}
DI void add_llc(int* p) {
  __hip_atomic_fetch_add(p, 1, __ATOMIC_RELAXED, __HIP_MEMORY_SCOPE_AGENT);
}
DI void drain_vm() { asm volatile("s_waitcnt vmcnt(0)" ::: "memory"); }
DI void membar() {
  __builtin_amdgcn_sched_barrier(0);
  asm volatile("" ::: "memory");
}
// bounded spin: converts any protocol bug into a fast wrong-answer, never a hang
DI void spin_ge(const int* p, int target) {
  for (int it = 0; it < (1 << 14); ++it) {
    if (ld_llc(p) >= target) return;
    __builtin_amdgcn_s_sleep(1);
  }
}
// 4 stores at byte offsets {0,1536,3072,4608}: 13-bit imm caps at 4095 -> two bases.
DI void st4_sc1(f16* b, f16 v0, f16 v1, f16 v2, f16 v3) {
  const f16* b2 = b + 1536;  // +3072 bytes
  asm volatile(
      "global_store_short %4, %0, off sc1\n\t"
      "global_store_short %4, %1, off offset:1536 sc1\n\t"
      "global_store_short %5, %2, off sc1\n\t"
      "global_store_short %5, %3, off offset:1536 sc1\n\t"
      "s_waitcnt vmcnt(0)"
      :: "v"(v0), "v"(v1), "v"(v2), "v"(v3), "v"(b), "v"(b2) : "memory");
}

// fence-free counting barrier; every thread drains its own (asm) stores first.
DI void gridbar_nf(int* bar, int nwg) {
  drain_vm();
  __syncthreads();
  if (threadIdx.x == 0) {
    int g = ld_llc(bar + 1);
    int old = __hip_atomic_fetch_add(bar, 1, __ATOMIC_RELAXED, __HIP_MEMORY_SCOPE_AGENT);
    if (old == nwg - 1) {
      __hip_atomic_store(bar, 0, __ATOMIC_RELAXED, __HIP_MEMORY_SCOPE_AGENT);
      add_llc(bar + 1);
    } else {
      for (int it = 0; it < (1 << 14) && ld_llc(bar + 1) == g; ++it)
        __builtin_amdgcn_s_sleep(1);
    }
  }
  __syncthreads();
}

// D = A*B (257x257 fp64), optional fused Taylor block; output via sc1 stores.
DI void mm257(double* __restrict__ D, const double* __restrict__ A, const double* __restrict__ Bm,
              int fj, const double* __restrict__ T1, const double* __restrict__ T2,
              const double* __restrict__ T3, int gtid, int nth) {
  double c0 = 0, c1 = 0, c2 = 0, c3 = 0;
  if (fj >= 0) {
    c0 = invfact(4 * fj); c1 = invfact(4 * fj + 1);
    c2 = invfact(4 * fj + 2); c3 = invfact(4 * fj + 3);
  }
  for (int e = gtid; e < N2; e += nth) {
    int i = e / 257, j = e - i * 257;
    const double* ar = A + (size_t)i * 257;
    const double* bc = Bm + j;
    double s0 = 0, s1 = 0, s2 = 0, s3 = 0;
    for (int k = 0; k < 256; k += 4) {
      s0 = fma(ar[k], bc[(size_t)k * 257], s0);
      s1 = fma(ar[k + 1], bc[(size_t)(k + 1) * 257], s1);
      s2 = fma(ar[k + 2], bc[(size_t)(k + 2) * 257], s2);
      s3 = fma(ar[k + 3], bc[(size_t)(k + 3) * 257], s3);
    }
    double s = ((s0 + s1) + (s2 + s3)) + ar[256] * bc[(size_t)256 * 257];
    if (fj >= 0) s += c0 * ((i == j) ? 1.0 : 0.0) + c1 * T1[e] + c2 * T2[e] + c3 * T3[e];
    st_d_sc1(D + e, s);
  }
}

// ---------------- K1: expm + all precomputation (128 WGs, fence-free) ----------------
__global__ __launch_bounds__(256) void k_setup(
    const float* __restrict__ dayW, const float* __restrict__ ex0, const float* __restrict__ Wx0,
    const float* __restrict__ exr, const float* __restrict__ Wxr,
    const float* __restrict__ eh, const float* __restrict__ em,
    const float* __restrict__ Wh, const float* __restrict__ Wm, const float* __restrict__ outW,
    double* __restrict__ X, float* __restrict__ w1f, float* __restrict__ AWt,
    float* __restrict__ btf, f16* __restrict__ gbuf, f16* __restrict__ wxcat,
    f16* __restrict__ outw, f16* __restrict__ dayWt, int* __restrict__ bar) {
  const int gtid = blockIdx.x * 256 + threadIdx.x;
  const int nth = 128 * 256;
  double* Ms = X;
  double* M2 = X + N2;
  double* M3 = X + 2 * N2;
  double* M4 = X + 3 * N2;
  double* H = X + 4 * N2;   // H0..H6 (7 buffers)
  double* S = X + 11 * N2;  // S0..S5 (6 buffers)

  // ---- phase 0: fills + scaled augmented matrix ----
  for (int e = gtid; e < N2; e += nth) {
    int i = e / 257, j = e - i * 257;
    double v = 0.0;
    if (i < 256) {
      double R = (2.0 * i + 1.0) / 256.0;
      if (j < 256) v = R * ((i < j) ? -1.0 : (((i - j) & 1) ? 1.0 : -1.0));
      else v = R * ((i & 1) ? -1.0 : 1.0);
    }
    st_d_sc1(Ms + e, v / 64.0);  // s = 6
  }
  for (int e = gtid; e < 576 * 896; e += nth) {  // wxcat [576][7168] = [Wx0 | ex0 | 0]
    int n = e / 896, kc = (e - n * 896) * 8;
    f16x8 v;
    if (n < 512) v = cvt8(Wx0 + (size_t)n * 7168 + kc);
    else if (n == 512) v = cvt8(ex0 + kc);
    else {
#pragma unroll
      for (int j = 0; j < 8; ++j) v[j] = (f16)0.f;
    }
    *reinterpret_cast<f16x8*>(wxcat + (size_t)n * 7168 + kc) = v;
  }
  for (int e = gtid; e < 48 * 64; e += nth) {  // outw [48][512]
    int n = e / 64, kc = (e - n * 64) * 8;
    f16x8 v;
    if (n < 41) v = cvt8(outW + (size_t)n * 512 + kc);
    else {
#pragma unroll
      for (int j = 0; j < 8; ++j) v[j] = (f16)0.f;
    }
    *reinterpret_cast<f16x8*>(outw + (size_t)n * 512 + kc) = v;
  }
  {  // dayWt[D][n][k] = dayW[D][k][n] via LDS tile transpose
    __shared__ float tile[64][65];
    for (int tt = blockIdx.x; tt < 24 * 64; tt += 128) {
      int D = tt >> 6; int r = tt & 63; int kb = (r >> 3) * 64; int nb = (r & 7) * 64;
      __syncthreads();
      for (int q = 0; q < 16; ++q) {
        int idx = threadIdx.x + q * 256; int kk = idx >> 6; int nn = idx & 63;
        tile[kk][nn] = dayW[(size_t)D * 262144 + (size_t)(kb + kk) * 512 + nb + nn];
      }
      __syncthreads();
      for (int q = 0; q < 2; ++q) {
        int cidx = threadIdx.x + q * 256; int nn = cidx >> 3; int kc = (cidx & 7) * 8;
        f16x8 v;
#pragma unroll
        for (int jj = 0; jj < 8; ++jj) v[jj] = (f16)tile[kc + jj][nn];
        *reinterpret_cast<f16x8*>(dayWt + (size_t)D * 262144 + (size_t)(nb + nn) * 512 + kb + kc) = v;
      }
    }
    __syncthreads();
  }
  gridbar_nf(bar, 128);

  // ---- expm: powers, PS-Horner (deg 24), 6 squarings — all unique buffers ----
  mm257(M2, Ms, Ms, -1, Ms, Ms, Ms, gtid, nth); gridbar_nf(bar, 128);
  mm257(M3, M2, Ms, -1, Ms, Ms, Ms, gtid, nth); gridbar_nf(bar, 128);
  mm257(M4, M2, M2, -1, Ms, Ms, Ms, gtid, nth);
  for (int e = gtid; e < N2; e += nth) {  // H0 = c24*I
    int i = e / 257, j = e - i * 257;
    st_d_sc1(H + e, (i == j) ? invfact(24) : 0.0);
  }
  gridbar_nf(bar, 128);
  for (int k = 0; k < 6; ++k) {  // Horner
    mm257(H + (size_t)(k + 1) * N2, H + (size_t)k * N2, M4, 5 - k, Ms, M2, M3, gtid, nth);
    gridbar_nf(bar, 128);
  }
  {
    const double* Ssrc = H + (size_t)6 * N2;
    for (int k = 0; k < 6; ++k) {  // squarings
      mm257(S + (size_t)k * N2, Ssrc, Ssrc, -1, Ms, Ms, Ms, gtid, nth);
      gridbar_nf(bar, 128);
      Ssrc = S + (size_t)k * N2;
    }
  }
  const double* E = S + (size_t)5 * N2;  // exp(aug)

  // ---- bt, w1, AWt ----
  for (int e = gtid; e < 256; e += nth) st_f_sc1(btf + e, (float)E[(size_t)e * 257 + 256]);
  for (int e = gtid; e < 5 * 512; e += nth) {
    int l = e / 512, n = e - l * 512;
    const float* wm = Wm + ((size_t)l * 512 + n) * 256;
    float s = 0.f;
    for (int j = 0; j < 256; ++j) s += (float)E[(size_t)j * 257 + 256] * wm[j];
    st_f_sc1(w1f + e, s);
  }
  for (int e = gtid; e < 5 * 512 * 256; e += nth) {
    int l = e / (512 * 256); int r = e - l * 512 * 256; int n = r >> 8; int i = r & 255;
    const double* Ec = E + i;
    const float* wm = Wm + ((size_t)l * 512 + n) * 256;
    float s0 = 0, s1 = 0, s2 = 0, s3 = 0;
    for (int j = 0; j < 256; j += 4) {
      s0 += (float)Ec[(size_t)j * 257] * wm[j];
      s1 += (float)Ec[(size_t)(j + 1) * 257] * wm[j + 1];
      s2 += (float)Ec[(size_t)(j + 2) * 257] * wm[j + 2];
      s3 += (float)Ec[(size_t)(j + 3) * 257] * wm[j + 3];
    }
    st_f_sc1(AWt + e, (s0 + s1) + (s2 + s3));
  }
  gridbar_nf(bar, 128);

  // ---- gbuf[l][n][k] fill (plain stores; consumed by later dispatches) ----
  for (int e = gtid; e < 5 * 768 * 160; e += nth) {
    int l = e / (768 * 160); int r = e - l * 768 * 160; int n = r / 160; int k = (r - n * 160) * 8;
    if (l == 0 && k >= 768) continue;
    f16x8 v;
    if (n < 512) {
      float w1n = w1f[l * 512 + n];
      if (k < 512) {
        const float* a = Wh + ((size_t)l * 512 + n) * 512 + k;
        const float* b = eh + (size_t)l * 512 + k;
#pragma unroll
        for (int jj = 0; jj < 8; ++jj) v[jj] = (f16)(a[jj] + b[jj] * w1n);
      } else if (k < 768) {
        int i = k - 512;
        const float* a = AWt + ((size_t)l * 512 + n) * 256 + i;
        const float* b = em + (size_t)l * 256 + i;
#pragma unroll
        for (int jj = 0; jj < 8; ++jj) v[jj] = (f16)(a[jj] + b[jj] * w1n);
      } else {
        int d = k - 768;
        const float* a = Wxr + ((size_t)(l - 1) * 512 + n) * 512 + d;
        const float* b = exr + (size_t)(l - 1) * 512 + d;
#pragma unroll
        for (int jj = 0; jj < 8; ++jj) v[jj] = (f16)(a[jj] + b[jj] * w1n);
      }
    } else {
      int jm = n - 512;
      float btn = btf[jm];
      if (k < 512) {
        const float* b = eh + (size_t)l * 512 + k;
#pragma unroll
        for (int jj = 0; jj < 8; ++jj) v[jj] = (f16)(b[jj] * btn);
      } else if (k < 768) {
        int i = k - 512;
        const double* a = E + (size_t)jm * 257 + i;
        const float* b = em + (size_t)l * 256 + i;
#pragma unroll
        for (int jj = 0; jj < 8; ++jj) v[jj] = (f16)((float)a[jj] + b[jj] * btn);
      } else {
        int d = k - 768;
        const float* b = exr + (size_t)(l - 1) * 512 + d;
#pragma unroll
        for (int jj = 0; jj < 8; ++jj) v[jj] = (f16)(b[jj] * btn);
      }
    }
    *reinterpret_cast<f16x8*>(gbuf + ((size_t)l * 768 + n) * 1280 + k) = v;
  }
}

// ---------------- K2: day-specific linear + softsign -> h1 (f16) ----------------
__global__ __launch_bounds__(256) void k_day(const float* __restrict__ x,
    const int* __restrict__ dayIdx, const float* __restrict__ dayb,
    const f16* __restrict__ dayWt, f16* __restrict__ h1) {
  __shared__ f16 As[64][40];
  __shared__ f16 Bs[256][40];
  const int bid = blockIdx.x;
  const int b = bid >> 5; const int r = bid & 31;
  const int t0 = (r >> 1) * 64; const int n0 = (r & 1) * 256;
  const int D = dayIdx[b];
  const int tid = threadIdx.x, lane = tid & 63, w = tid >> 6, q4 = lane >> 4;
  const float* xb = x + ((size_t)b * 1024 + t0) * 512;
  const f16* Wt = dayWt + (size_t)D * 262144 + (size_t)n0 * 512;
  f32x4 acc[16];
#pragma unroll
  for (int i = 0; i < 16; ++i) acc[i] = (f32x4){0.f, 0.f, 0.f, 0.f};
  for (int kt = 0; kt < 16; ++kt) {
    const int k0 = kt * 32;
    __syncthreads();
    { int row = tid >> 2, c8 = (tid & 3) * 8;
      *reinterpret_cast<f16x8*>(&As[row][c8]) = cvt8(xb + (size_t)row * 512 + k0 + c8); }
    for (int q = 0; q < 4; ++q) {
      int idx = tid + q * 256; int row = idx >> 2; int c8 = (idx & 3) * 8;
      *reinterpret_cast<f16x8*>(&Bs[row][c8]) = ldg8(Wt + (size_t)row * 512 + k0 + c8);
    }
    __syncthreads();
    f16x8 a = *reinterpret_cast<const f16x8*>(&As[w * 16 + (lane & 15)][q4 * 8]);
#pragma unroll
    for (int nt2 = 0; nt2 < 16; ++nt2) {
      f16x8 bb = *reinterpret_cast<const f16x8*>(&Bs[nt2 * 16 + (lane & 15)][q4 * 8]);
      acc[nt2] = mfma16(a, bb, acc[nt2]);
    }
  }
#pragma unroll
  for (int nt2 = 0; nt2 < 16; ++nt2) {
    int n = n0 + nt2 * 16 + (lane & 15);
    float db = dayb[(size_t)D * 512 + n];
#pragma unroll
    for (int i = 0; i < 4; ++i) {
      int t = t0 + w * 16 + q4 * 4 + i;
      float v = acc[nt2][i] + db;
      v = v / (1.f + fabsf(v));
      h1[((size_t)b * 1024 + t) * 512 + n] = (f16)v;
    }
  }
}

// ---------------- K3: layer-0 input GEMM (patch-gathered) -> xw0 [8192][576] f32 ----------------
__global__ __launch_bounds__(256) void k_xw0(const f16* __restrict__ h1,
    const f16* __restrict__ wxcat, float* __restrict__ xw0) {
  __shared__ f16 As[128][40];
  __shared__ f16 Bs[96][40];
  const int bid = blockIdx.x;
  const int mt = bid / 6; const int nb = bid - mt * 6;
  const int m0 = mt * 128; const int n0 = nb * 96;
  const int tid = threadIdx.x, lane = tid & 63, w = tid >> 6, q4 = lane >> 4;
  f32x4 acc[2][6];
#pragma unroll
  for (int a = 0; a < 2; ++a)
#pragma unroll
    for (int b = 0; b < 6; ++b) acc[a][b] = (f32x4){0.f, 0.f, 0.f, 0.f};
  for (int kt = 0; kt < 224; ++kt) {
    const int k0 = kt * 32; const int p = k0 >> 9; const int kd = k0 & 511;
    __syncthreads();
    for (int q = 0; q < 2; ++q) {
      int idx = tid + q * 256; int row = idx >> 2; int c8 = (idx & 3) * 8;
      int m = m0 + row; int b = m >> 8; int tp = m & 255; if (tp > 252) tp = 252;
      *reinterpret_cast<f16x8*>(&As[row][c8]) =
          ldg8(h1 + ((size_t)b * 1024 + (size_t)tp * 4 + p) * 512 + kd + c8);
    }
    for (int q = 0; q < 2; ++q) {
      int idx = tid + q * 256;
      if (idx < 384) {
        int row = idx >> 2; int c8 = (idx & 3) * 8;
        *reinterpret_cast<f16x8*>(&Bs[row][c8]) =
            ldg8(wxcat + (size_t)(n0 + row) * 7168 + k0 + c8);
      }
    }
    __syncthreads();
#pragma unroll
    for (int mb = 0; mb < 2; ++mb) {
      f16x8 a = *reinterpret_cast<const f16x8*>(&As[w * 32 + mb * 16 + (lane & 15)][q4 * 8]);
#pragma unroll
      for (int nt2 = 0; nt2 < 6; ++nt2) {
        f16x8 bb = *reinterpret_cast<const f16x8*>(&Bs[nt2 * 16 + (lane & 15)][q4 * 8]);
        acc[mb][nt2] = mfma16(a, bb, acc[mb][nt2]);
      }
    }
  }
#pragma unroll
  for (int mb = 0; mb < 2; ++mb)
#pragma unroll
    for (int nt2 = 0; nt2 < 6; ++nt2)
#pragma unroll
      for (int i = 0; i < 4; ++i) {
        int m = m0 + w * 32 + mb * 16 + q4 * 4 + i;
        int n = n0 + nt2 * 16 + (lane & 15);
        xw0[(size_t)m * 576 + n] = acc[mb][nt2][i];
      }
}

// ---------------- K4: pipelined LMU recurrence (single all-LLC protocol) ----------------
template <int KK>
DI void rec_run(int l, int c, int tid, const f16* __restrict__ gbuf, f16* __restrict__ sbuf,
                const float* __restrict__ xw0, const float* __restrict__ w1f,
                const float* __restrict__ btf, const float* __restrict__ h0,
                const float* __restrict__ m0, int* done, f16* bflds) {
  const int lane = tid & 63, w = tid >> 6;
  const int mb = w / 3, nt = w % 3;
  const int nbase = c * 48 + nt * 16;
  const int ncol = nbase + (lane & 15);
  const int q4 = lane >> 4;

  // ---- t=0 state init -> LLC ----
  for (int r = tid; r < 32 * 48; r += 384) {
    int row = r / 48; int col = c * 48 + (r - row * 48);
    float v = (col < 512) ? h0[(size_t)l * 512 + col] : m0[(size_t)l * 256 + col - 512];
    st_h_sc1(sbuf + (size_t)l * LSTRIDE + (size_t)row * 768 + col, (f16)v);
  }

  // ---- weights into registers (+ LDS for the x-tail of KK=40) ----
  const f16* gb = gbuf + ((size_t)l * 768 + ncol) * 1280 + (size_t)q4 * 8;
  constexpr int NREG = (KK > 32) ? 32 : KK;
  f16x8 bf[NREG];
#pragma unroll
  for (int kk = 0; kk < NREG; ++kk) bf[kk] = ldg8(gb + (size_t)kk * 32);
  if (KK == 40) {
#pragma unroll
    for (int kk = 32; kk < 40; ++kk) {
      f16x8 v = ldg8(gb + (size_t)kk * 32);
      *reinterpret_cast<f16x8*>(bflds + ((size_t)(w * 8 + (kk - 32)) * 64 + lane) * 8) = v;
    }
  }
  float w1n = 0.f, btn = 0.f;
  if (KK == 24) {
    if (ncol < 512) w1n = w1f[ncol];
    else btn = btf[ncol - 512];
  }
  drain_vm();       // every thread drains its own init sc1 stores
  __syncthreads();  // + bflds visible
  if (tid == 0) add_llc(done + l * 256);

  for (int t = 0; t < 253; ++t) {
    if (tid == 0) {
      spin_ge(done + l * 256 + t, 16);
      if (l > 0) spin_ge(done + (l - 1) * 256 + t + 1, 16);
    }
    __builtin_amdgcn_s_barrier();
    membar();

    const int arow = mb * 16 + (lane & 15);
    const f16* s0 = sbuf + (size_t)l * LSTRIDE + ((size_t)t * 32 + arow) * 768 + (size_t)q4 * 8;
    f32x4 acc = {0.f, 0.f, 0.f, 0.f};
#pragma unroll
    for (int kk = 0; kk < 24; ++kk) acc = mfma16(ldg8(s0 + (size_t)kk * 32), bf[kk < NREG ? kk : 0], acc);
    if (KK == 40) {
      const f16* s1 = sbuf + (size_t)(l - 1) * LSTRIDE + ((size_t)(t + 1) * 32 + arow) * 768 + (size_t)q4 * 8;
#pragma unroll
      for (int kk = 24; kk < 32; ++kk) acc = mfma16(ldg8(s1 + (size_t)(kk - 24) * 32), bf[kk < NREG ? kk : 0], acc);
#pragma unroll
      for (int kk = 32; kk < 40; ++kk) {
        f16x8 bb = *reinterpret_cast<const f16x8*>(bflds + ((size_t)(w * 8 + (kk - 32)) * 64 + lane) * 8);
        acc = mfma16(ldg8(s1 + (size_t)(kk - 24) * 32), bb, acc);
      }
    }

    f16 v4[4];
#pragma unroll
    for (int i = 0; i < 4; ++i) {
      const int brow = mb * 16 + q4 * 4 + i;
      float v = acc[i];
      if (KK == 24) {
        const float* xr = xw0 + ((size_t)brow * 256 + t) * 576;
        float xe = xr[512];
        v += (ncol < 512) ? (xr[ncol] + xe * w1n) : (xe * btn);
      }
      if (ncol < 512) v = tanhf(v);
      v4[i] = (f16)v;
    }
    f16* dst = sbuf + (size_t)l * LSTRIDE +
               ((size_t)(t + 1) * 32 + (size_t)(mb * 16 + q4 * 4)) * 768 + ncol;
    st4_sc1(dst, v4[0], v4[1], v4[2], v4[3]);  // ends with per-thread vmcnt(0)

    __builtin_amdgcn_s_barrier();  // all threads' sc1 stores are at LLC
    if (tid == 0) add_llc(done + l * 256 + t + 1);
  }
}

__global__ __launch_bounds__(384, 2) void k_rec(const f16* __restrict__ gbuf, f16* __restrict__ sbuf,
    const float* __restrict__ xw0, const float* __restrict__ w1f,
    const float* __restrict__ btf, const float* __restrict__ h0,
    const float* __restrict__ m0, int* __restrict__ done) {
  __shared__ f16 bflds[6 * 8 * 64 * 8];
  const int l = blockIdx.x >> 4;  // grid = 80
  const int c = blockIdx.x & 15;
  if (l == 0)
    rec_run<24>(0, c, threadIdx.x, gbuf, sbuf, xw0, w1f, btf, h0, m0, done, bflds);
  else
    rec_run<40>(l, c, threadIdx.x, gbuf, sbuf, xw0, w1f, btf, h0, m0, done, bflds);
}

// ---------------- K5: output projection ----------------
__global__ __launch_bounds__(256) void k_out(const f16* __restrict__ sbuf4,
    const f16* __restrict__ outw, const float* __restrict__ outb, float* __restrict__ out) {
  const int bid = blockIdx.x; const int b = bid >> 2; const int tp0 = (bid & 3) * 64;
  const int tid = threadIdx.x, lane = tid & 63, w = tid >> 6, q4 = lane >> 4;
  f32x4 acc[3];
#pragma unroll
  for (int i = 0; i < 3; ++i) acc[i] = (f32x4){0.f, 0.f, 0.f, 0.f};
  int tq = tp0 + w * 16 + (lane & 15) + 1;
  const int tau = tq > 253 ? 253 : tq;
  const f16* arow = sbuf4 + ((size_t)tau * 32 + b) * 768 + (size_t)q4 * 8;
#pragma unroll
  for (int kk = 0; kk < 16; ++kk) {
    f16x8 a = ldg8(arow + (size_t)kk * 32);
#pragma unroll
    for (int nt2 = 0; nt2 < 3; ++nt2) {
      f16x8 bb = ldg8(outw + (size_t)(nt2 * 16 + (lane & 15)) * 512 + kk * 32 + q4 * 8);
      acc[nt2] = mfma16(a, bb, acc[nt2]);
    }
  }
#pragma unroll
  for (int nt2 = 0; nt2 < 3; ++nt2) {
    int cc = nt2 * 16 + (lane & 15);
    if (cc < 41) {
      float ob = outb[cc];
#pragma unroll
      for (int i = 0; i < 4; ++i) {
        int tp = tp0 + w * 16 + q4 * 4 + i;
        if (tp < 253) out[((size_t)b * 253 + tp) * 41 + cc] = acc[nt2][i] + ob;
      }
    }
  }
}

extern "C" void kernel_launch(void* const* d_in, const int* in_sizes, int n_in,
                              void* d_out, int out_size, void* d_ws, size_t ws_size,
                              hipStream_t stream) {
  const float* x      = (const float*)d_in[0];
  const int*   dayIdx = (const int*)d_in[1];
  const float* day_W  = (const float*)d_in[2];
  const float* day_b  = (const float*)d_in[3];
  const float* e_x0   = (const float*)d_in[4];
  const float* W_x0   = (const float*)d_in[5];
  const float* e_xr   = (const float*)d_in[6];
  const float* W_xr   = (const float*)d_in[7];
  const float* e_h    = (const float*)d_in[8];
  const float* e_m    = (const float*)d_in[9];
  const float* W_h    = (const float*)d_in[10];
  const float* W_m    = (const float*)d_in[11];
  const float* h0     = (const float*)d_in[12];
  const float* m0     = (const float*)d_in[13];
  const float* out_W  = (const float*)d_in[14];
  const float* out_b  = (const float*)d_in[15];
  float* outp = (float*)d_out;

  char* w = (char*)d_ws;
  size_t o = 0;
  auto al = [&](size_t n) { void* p = w + o; o = (o + n + 255) & ~(size_t)255; return p; };

  int*   flags = (int*)  al(16384);
  f16*   gbuf  = (f16*)  al((size_t)5 * 768 * 1280 * 2);
  f16*   outw  = (f16*)  al((size_t)48 * 512 * 2);
  float* xw0   = (float*)al((size_t)8192 * 576 * 4);
  float* w1f   = (float*)al((size_t)5 * 512 * 4);
  float* btf   = (float*)al(256 * 4);

  // overlay: setup temporaries (X, AWt, dayWt, wxcat, h1) are dead before
  // k_rec writes sbuf — alias them over the sbuf region. (Dispatch-boundary
  // release/acquire flushes dirty L2 lines between kernels, so no aliased
  // stale-line writeback can corrupt sbuf.)
  const size_t XB    = ((size_t)17 * N2 * 8 + 255) & ~(size_t)255;
  const size_t AWTB  = ((size_t)5 * 512 * 256 * 4 + 255) & ~(size_t)255;
  const size_t DAYB  = ((size_t)24 * 512 * 512 * 2 + 255) & ~(size_t)255;
  const size_t WXB   = ((size_t)576 * 7168 * 2 + 255) & ~(size_t)255;
  const size_t H1B   = ((size_t)32 * 1024 * 512 * 2 + 255) & ~(size_t)255;
  const size_t SBUFB = (size_t)5 * LSTRIDE * 2;
  size_t ovb = XB + AWTB + DAYB + WXB + H1B;
  if (SBUFB > ovb) ovb = SBUFB;
  char* ov = (char*)al(ovb);
  double* X     = (double*)ov;
  float*  AWt   = (float*)(ov + XB);
  f16*    dayWt = (f16*)(ov + XB + AWTB);
  f16*    wxcat = (f16*)(ov + XB + AWTB + DAYB);
  f16*    h1    = (f16*)(ov + XB + AWTB + DAYB + WXB);
  f16*    sbuf  = (f16*)ov;

  if (o > ws_size) return;  // workspace too small -> fail loudly
  (void)in_sizes; (void)n_in; (void)out_size;

  hipMemsetAsync(flags, 0, 16384, stream);
  k_setup<<<128, 256, 0, stream>>>(day_W, e_x0, W_x0, e_xr, W_xr, e_h, e_m, W_h, W_m,
                                   out_W, X, w1f, AWt, btf, gbuf, wxcat, outw, dayWt,
                                   flags + 2048);
  k_day<<<1024, 256, 0, stream>>>(x, dayIdx, day_b, dayWt, h1);
  k_xw0<<<384, 256, 0, stream>>>(h1, wxcat, xw0);
  k_rec<<<80, 384, 0, stream>>>(gbuf, sbuf, xw0, w1f, btf, h0, m0, flags);
  k_out<<<128, 256, 0, stream>>>(sbuf + (size_t)4 * LSTRIDE, outw, out_b, outp);
}

// Round 5
// 4100.889 us; speedup vs baseline: 1.4653x; 1.0368x over previous
//
#include <hip/hip_runtime.h>
#include <hip/hip_fp16.h>

typedef _Float16 f16;
typedef _Float16 f16x8 __attribute__((ext_vector_type(8)));
typedef _Float16 f16x4 __attribute__((ext_vector_type(4)));
typedef float f32x4 __attribute__((ext_vector_type(4)));
typedef int int4v __attribute__((ext_vector_type(4)));

#define DI static __device__ __forceinline__

constexpr int N2 = 257 * 257;
#define LSTRIDE ((size_t)254 * 32 * 768)

DI f32x4 mfma16(f16x8 a, f16x8 b, f32x4 c) {
  return __builtin_amdgcn_mfma_f32_16x16x32_f16(a, b, c, 0, 0, 0);
}
DI f16x8 ldg8(const f16* p) { return *reinterpret_cast<const f16x8*>(p); }
DI f16x8 cvt8(const float* s) {
  f16x8 v;
#pragma unroll
  for (int j = 0; j < 8; ++j) v[j] = (f16)s[j];
  return v;
}
DI double invfact(int k) {
  double f = 1.0;
  for (int i = 2; i <= k; ++i) f *= (double)i;
  return 1.0 / f;
}

// ---- visibility helpers: sc1 = write-through to LLC; flags via LLC loads/stores ----
DI void st_d_sc1(double* p, double v) {
  asm volatile("global_store_dwordx2 %0, %1, off sc1" :: "v"(p), "v"(v) : "memory");
}
DI void st_f_sc1(float* p, float v) {
  asm volatile("global_store_dword %0, %1, off sc1" :: "v"(p), "v"(v) : "memory");
}
DI void st_h_sc1(f16* p, f16 v) {
  asm volatile("global_store_short %0, %1, off sc1" :: "v"(p), "v"(v) : "memory");
}
DI void st_b_sc1(unsigned char* p, int v) {  // fire-and-forget flag byte
  asm volatile("global_store_byte %0, %1, off sc1" :: "v"(p), "v"(v) : "memory");
}
DI void st8_sc1(f16* p, f16x4 v) {  // coalesced 8B state store + personal drain
  asm volatile("global_store_dwordx2 %0, %1, off sc1\n\ts_waitcnt vmcnt(0)"
               :: "v"(p), "v"(v) : "memory");
}
DI int ld_llc(const int* p) {
  return __hip_atomic_load(p, __ATOMIC_RELAXED, __HIP_MEMORY_SCOPE_AGENT);
}
DI void add_llc(int* p) {
  __hip_atomic_fetch_add(p, 1, __ATOMIC_RELAXED, __HIP_MEMORY_SCOPE_AGENT);
}
DI void drain_vm() { asm volatile("s_waitcnt vmcnt(0)" ::: "memory"); }
DI void membar() {
  __builtin_amdgcn_sched_barrier(0);
  asm volatile("" ::: "memory");
}
DI bool all_one(int4v a) {
  return a.x == 0x01010101 && a.y == 0x01010101 && a.z == 0x01010101 && a.w == 0x01010101;
}
// bounded polls: a protocol bug becomes a fast wrong-answer, never a hang
DI void poll_one(const int* p) {
  for (int it = 0; it < (1 << 14); ++it) {
    int4v a;
    asm volatile("global_load_dwordx4 %0, %1, off sc1\n\ts_waitcnt vmcnt(0)"
                 : "=v"(a) : "v"(p) : "memory");
    if (all_one(a)) return;
    __builtin_amdgcn_s_sleep(1);
  }
}
DI void poll_two(const int* pa, const int* pb) {
  for (int it = 0; it < (1 << 14); ++it) {
    int4v a, b;
    asm volatile(
        "global_load_dwordx4 %0, %2, off sc1\n\t"
        "global_load_dwordx4 %1, %3, off sc1\n\t"
        "s_waitcnt vmcnt(0)"
        : "=&v"(a), "=&v"(b) : "v"(pa), "v"(pb) : "memory");
    if (all_one(a) && all_one(b)) return;
    __builtin_amdgcn_s_sleep(1);
  }
}
DI float tanh_fast(float x) {
  x = fminf(9.f, fmaxf(-9.f, x));
  float e = __expf(2.f * x);
  return __fdividef(e - 1.f, e + 1.f);
}

// fence-free counting barrier (k_setup only); every thread drains its own stores first.
DI void gridbar_nf(int* bar, int nwg) {
  drain_vm();
  __syncthreads();
  if (threadIdx.x == 0) {
    int g = ld_llc(bar + 1);
    int old = __hip_atomic_fetch_add(bar, 1, __ATOMIC_RELAXED, __HIP_MEMORY_SCOPE_AGENT);
    if (old == nwg - 1) {
      __hip_atomic_store(bar, 0, __ATOMIC_RELAXED, __HIP_MEMORY_SCOPE_AGENT);
      add_llc(bar + 1);
    } else {
      for (int it = 0; it < (1 << 14) && ld_llc(bar + 1) == g; ++it)
        __builtin_amdgcn_s_sleep(1);
    }
  }
  __syncthreads();
}

// D = A*B (257x257 fp64), optional fused Taylor block; output via sc1 stores.
DI void mm257(double* __restrict__ D, const double* __restrict__ A, const double* __restrict__ Bm,
              int fj, const double* __restrict__ T1, const double* __restrict__ T2,
              const double* __restrict__ T3, int gtid, int nth) {
  double c0 = 0, c1 = 0, c2 = 0, c3 = 0;
  if (fj >= 0) {
    c0 = invfact(4 * fj); c1 = invfact(4 * fj + 1);
    c2 = invfact(4 * fj + 2); c3 = invfact(4 * fj + 3);
  }
  for (int e = gtid; e < N2; e += nth) {
    int i = e / 257, j = e - i * 257;
    const double* ar = A + (size_t)i * 257;
    const double* bc = Bm + j;
    double s0 = 0, s1 = 0, s2 = 0, s3 = 0;
    for (int k = 0; k < 256; k += 4) {
      s0 = fma(ar[k], bc[(size_t)k * 257], s0);
      s1 = fma(ar[k + 1], bc[(size_t)(k + 1) * 257], s1);
      s2 = fma(ar[k + 2], bc[(size_t)(k + 2) * 257], s2);
      s3 = fma(ar[k + 3], bc[(size_t)(k + 3) * 257], s3);
    }
    double s = ((s0 + s1) + (s2 + s3)) + ar[256] * bc[(size_t)256 * 257];
    if (fj >= 0) s += c0 * ((i == j) ? 1.0 : 0.0) + c1 * T1[e] + c2 * T2[e] + c3 * T3[e];
    st_d_sc1(D + e, s);
  }
}

// ---------------- K1: expm + all precomputation (128 WGs, fence-free) ----------------
__global__ __launch_bounds__(256) void k_setup(
    const float* __restrict__ dayW, const float* __restrict__ ex0, const float* __restrict__ Wx0,
    const float* __restrict__ exr, const float* __restrict__ Wxr,
    const float* __restrict__ eh, const float* __restrict__ em,
    const float* __restrict__ Wh, const float* __restrict__ Wm, const float* __restrict__ outW,
    double* __restrict__ X, float* __restrict__ w1f, float* __restrict__ AWt,
    float* __restrict__ btf, f16* __restrict__ gbuf, f16* __restrict__ wxcat,
    f16* __restrict__ outw, f16* __restrict__ dayWt, int* __restrict__ bar) {
  const int gtid = blockIdx.x * 256 + threadIdx.x;
  const int nth = 128 * 256;
  double* Ms = X;
  double* M2 = X + N2;
  double* M3 = X + 2 * N2;
  double* M4 = X + 3 * N2;
  double* H = X + 4 * N2;   // H0..H6 (7 buffers)
  double* S = X + 11 * N2;  // S0..S5 (6 buffers)

  // ---- phase 0: fills + scaled augmented matrix ----
  for (int e = gtid; e < N2; e += nth) {
    int i = e / 257, j = e - i * 257;
    double v = 0.0;
    if (i < 256) {
      double R = (2.0 * i + 1.0) / 256.0;
      if (j < 256) v = R * ((i < j) ? -1.0 : (((i - j) & 1) ? 1.0 : -1.0));
      else v = R * ((i & 1) ? -1.0 : 1.0);
    }
    st_d_sc1(Ms + e, v / 64.0);  // s = 6
  }
  for (int e = gtid; e < 576 * 896; e += nth) {  // wxcat [576][7168] = [Wx0 | ex0 | 0]
    int n = e / 896, kc = (e - n * 896) * 8;
    f16x8 v;
    if (n < 512) v = cvt8(Wx0 + (size_t)n * 7168 + kc);
    else if (n == 512) v = cvt8(ex0 + kc);
    else {
#pragma unroll
      for (int j = 0; j < 8; ++j) v[j] = (f16)0.f;
    }
    *reinterpret_cast<f16x8*>(wxcat + (size_t)n * 7168 + kc) = v;
  }
  for (int e = gtid; e < 48 * 64; e += nth) {  // outw [48][512]
    int n = e / 64, kc = (e - n * 64) * 8;
    f16x8 v;
    if (n < 41) v = cvt8(outW + (size_t)n * 512 + kc);
    else {
#pragma unroll
      for (int j = 0; j < 8; ++j) v[j] = (f16)0.f;
    }
    *reinterpret_cast<f16x8*>(outw + (size_t)n * 512 + kc) = v;
  }
  {  // dayWt[D][n][k] = dayW[D][k][n] via LDS tile transpose
    __shared__ float tile[64][65];
    for (int tt = blockIdx.x; tt < 24 * 64; tt += 128) {
      int D = tt >> 6; int r = tt & 63; int kb = (r >> 3) * 64; int nb = (r & 7) * 64;
      __syncthreads();
      for (int q = 0; q < 16; ++q) {
        int idx = threadIdx.x + q * 256; int kk = idx >> 6; int nn = idx & 63;
        tile[kk][nn] = dayW[(size_t)D * 262144 + (size_t)(kb + kk) * 512 + nb + nn];
      }
      __syncthreads();
      for (int q = 0; q < 2; ++q) {
        int cidx = threadIdx.x + q * 256; int nn = cidx >> 3; int kc = (cidx & 7) * 8;
        f16x8 v;
#pragma unroll
        for (int jj = 0; jj < 8; ++jj) v[jj] = (f16)tile[kc + jj][nn];
        *reinterpret_cast<f16x8*>(dayWt + (size_t)D * 262144 + (size_t)(nb + nn) * 512 + kb + kc) = v;
      }
    }
    __syncthreads();
  }
  gridbar_nf(bar, 128);

  // ---- expm: powers, PS-Horner (deg 24), 6 squarings — all unique buffers ----
  mm257(M2, Ms, Ms, -1, Ms, Ms, Ms, gtid, nth); gridbar_nf(bar, 128);
  mm257(M3, M2, Ms, -1, Ms, Ms, Ms, gtid, nth); gridbar_nf(bar, 128);
  mm257(M4, M2, M2, -1, Ms, Ms, Ms, gtid, nth);
  for (int e = gtid; e < N2; e += nth) {  // H0 = c24*I
    int i = e / 257, j = e - i * 257;
    st_d_sc1(H + e, (i == j) ? invfact(24) : 0.0);
  }
  gridbar_nf(bar, 128);
  for (int k = 0; k < 6; ++k) {  // Horner
    mm257(H + (size_t)(k + 1) * N2, H + (size_t)k * N2, M4, 5 - k, Ms, M2, M3, gtid, nth);
    gridbar_nf(bar, 128);
  }
  {
    const double* Ssrc = H + (size_t)6 * N2;
    for (int k = 0; k < 6; ++k) {  // squarings
      mm257(S + (size_t)k * N2, Ssrc, Ssrc, -1, Ms, Ms, Ms, gtid, nth);
      gridbar_nf(bar, 128);
      Ssrc = S + (size_t)k * N2;
    }
  }
  const double* E = S + (size_t)5 * N2;  // exp(aug)

  // ---- bt, w1, AWt ----
  for (int e = gtid; e < 256; e += nth) st_f_sc1(btf + e, (float)E[(size_t)e * 257 + 256]);
  for (int e = gtid; e < 5 * 512; e += nth) {
    int l = e / 512, n = e - l * 512;
    const float* wm = Wm + ((size_t)l * 512 + n) * 256;
    float s = 0.f;
    for (int j = 0; j < 256; ++j) s += (float)E[(size_t)j * 257 + 256] * wm[j];
    st_f_sc1(w1f + e, s);
  }
  for (int e = gtid; e < 5 * 512 * 256; e += nth) {
    int l = e / (512 * 256); int r = e - l * 512 * 256; int n = r >> 8; int i = r & 255;
    const double* Ec = E + i;
    const float* wm = Wm + ((size_t)l * 512 + n) * 256;
    float s0 = 0, s1 = 0, s2 = 0, s3 = 0;
    for (int j = 0; j < 256; j += 4) {
      s0 += (float)Ec[(size_t)j * 257] * wm[j];
      s1 += (float)Ec[(size_t)(j + 1) * 257] * wm[j + 1];
      s2 += (float)Ec[(size_t)(j + 2) * 257] * wm[j + 2];
      s3 += (float)Ec[(size_t)(j + 3) * 257] * wm[j + 3];
    }
    st_f_sc1(AWt + e, (s0 + s1) + (s2 + s3));
  }
  gridbar_nf(bar, 128);

  // ---- gbuf[l][n][k] fill (plain stores; consumed by later dispatches) ----
  for (int e = gtid; e < 5 * 768 * 160; e += nth) {
    int l = e / (768 * 160); int r = e - l * 768 * 160; int n = r / 160; int k = (r - n * 160) * 8;
    if (l == 0 && k >= 768) continue;
    f16x8 v;
    if (n < 512) {
      float w1n = w1f[l * 512 + n];
      if (k < 512) {
        const float* a = Wh + ((size_t)l * 512 + n) * 512 + k;
        const float* b = eh + (size_t)l * 512 + k;
#pragma unroll
        for (int jj = 0; jj < 8; ++jj) v[jj] = (f16)(a[jj] + b[jj] * w1n);
      } else if (k < 768) {
        int i = k - 512;
        const float* a = AWt + ((size_t)l * 512 + n) * 256 + i;
        const float* b = em + (size_t)l * 256 + i;
#pragma unroll
        for (int jj = 0; jj < 8; ++jj) v[jj] = (f16)(a[jj] + b[jj] * w1n);
      } else {
        int d = k - 768;
        const float* a = Wxr + ((size_t)(l - 1) * 512 + n) * 512 + d;
        const float* b = exr + (size_t)(l - 1) * 512 + d;
#pragma unroll
        for (int jj = 0; jj < 8; ++jj) v[jj] = (f16)(a[jj] + b[jj] * w1n);
      }
    } else {
      int jm = n - 512;
      float btn = btf[jm];
      if (k < 512) {
        const float* b = eh + (size_t)l * 512 + k;
#pragma unroll
        for (int jj = 0; jj < 8; ++jj) v[jj] = (f16)(b[jj] * btn);
      } else if (k < 768) {
        int i = k - 512;
        const double* a = E + (size_t)jm * 257 + i;
        const float* b = em + (size_t)l * 256 + i;
#pragma unroll
        for (int jj = 0; jj < 8; ++jj) v[jj] = (f16)((float)a[jj] + b[jj] * btn);
      } else {
        int d = k - 768;
        const float* b = exr + (size_t)(l - 1) * 512 + d;
#pragma unroll
        for (int jj = 0; jj < 8; ++jj) v[jj] = (f16)(b[jj] * btn);
      }
    }
    *reinterpret_cast<f16x8*>(gbuf + ((size_t)l * 768 + n) * 1280 + k) = v;
  }
}

// ---------------- K2: day-specific linear + softsign -> h1 (f16) ----------------
__global__ __launch_bounds__(256) void k_day(const float* __restrict__ x,
    const int* __restrict__ dayIdx, const float* __restrict__ dayb,
    const f16* __restrict__ dayWt, f16* __restrict__ h1) {
  __shared__ f16 As[64][40];
  __shared__ f16 Bs[256][40];
  const int bid = blockIdx.x;
  const int b = bid >> 5; const int r = bid & 31;
  const int t0 = (r >> 1) * 64; const int n0 = (r & 1) * 256;
  const int D = dayIdx[b];
  const int tid = threadIdx.x, lane = tid & 63, w = tid >> 6, q4 = lane >> 4;
  const float* xb = x + ((size_t)b * 1024 + t0) * 512;
  const f16* Wt = dayWt + (size_t)D * 262144 + (size_t)n0 * 512;
  f32x4 acc[16];
#pragma unroll
  for (int i = 0; i < 16; ++i) acc[i] = (f32x4){0.f, 0.f, 0.f, 0.f};
  for (int kt = 0; kt < 16; ++kt) {
    const int k0 = kt * 32;
    __syncthreads();
    { int row = tid >> 2, c8 = (tid & 3) * 8;
      *reinterpret_cast<f16x8*>(&As[row][c8]) = cvt8(xb + (size_t)row * 512 + k0 + c8); }
    for (int q = 0; q < 4; ++q) {
      int idx = tid + q * 256; int row = idx >> 2; int c8 = (idx & 3) * 8;
      *reinterpret_cast<f16x8*>(&Bs[row][c8]) = ldg8(Wt + (size_t)row * 512 + k0 + c8);
    }
    __syncthreads();
    f16x8 a = *reinterpret_cast<const f16x8*>(&As[w * 16 + (lane & 15)][q4 * 8]);
#pragma unroll
    for (int nt2 = 0; nt2 < 16; ++nt2) {
      f16x8 bb = *reinterpret_cast<const f16x8*>(&Bs[nt2 * 16 + (lane & 15)][q4 * 8]);
      acc[nt2] = mfma16(a, bb, acc[nt2]);
    }
  }
#pragma unroll
  for (int nt2 = 0; nt2 < 16; ++nt2) {
    int n = n0 + nt2 * 16 + (lane & 15);
    float db = dayb[(size_t)D * 512 + n];
#pragma unroll
    for (int i = 0; i < 4; ++i) {
      int t = t0 + w * 16 + q4 * 4 + i;
      float v = acc[nt2][i] + db;
      v = v / (1.f + fabsf(v));
      h1[((size_t)b * 1024 + t) * 512 + n] = (f16)v;
    }
  }
}

// ---------------- K3: layer-0 input GEMM (patch-gathered) -> xw0 [8192][576] f32 ----------------
__global__ __launch_bounds__(256) void k_xw0(const f16* __restrict__ h1,
    const f16* __restrict__ wxcat, float* __restrict__ xw0) {
  __shared__ f16 As[128][40];
  __shared__ f16 Bs[96][40];
  const int bid = blockIdx.x;
  const int mt = bid / 6; const int nb = bid - mt * 6;
  const int m0 = mt * 128; const int n0 = nb * 96;
  const int tid = threadIdx.x, lane = tid & 63, w = tid >> 6, q4 = lane >> 4;
  f32x4 acc[2][6];
#pragma unroll
  for (int a = 0; a < 2; ++a)
#pragma unroll
    for (int b = 0; b < 6; ++b) acc[a][b] = (f32x4){0.f, 0.f, 0.f, 0.f};
  for (int kt = 0; kt < 224; ++kt) {
    const int k0 = kt * 32; const int p = k0 >> 9; const int kd = k0 & 511;
    __syncthreads();
    for (int q = 0; q < 2; ++q) {
      int idx = tid + q * 256; int row = idx >> 2; int c8 = (idx & 3) * 8;
      int m = m0 + row; int b = m >> 8; int tp = m & 255; if (tp > 252) tp = 252;
      *reinterpret_cast<f16x8*>(&As[row][c8]) =
          ldg8(h1 + ((size_t)b * 1024 + (size_t)tp * 4 + p) * 512 + kd + c8);
    }
    for (int q = 0; q < 2; ++q) {
      int idx = tid + q * 256;
      if (idx < 384) {
        int row = idx >> 2; int c8 = (idx & 3) * 8;
        *reinterpret_cast<f16x8*>(&Bs[row][c8]) =
            ldg8(wxcat + (size_t)(n0 + row) * 7168 + k0 + c8);
      }
    }
    __syncthreads();
#pragma unroll
    for (int mb = 0; mb < 2; ++mb) {
      f16x8 a = *reinterpret_cast<const f16x8*>(&As[w * 32 + mb * 16 + (lane & 15)][q4 * 8]);
#pragma unroll
      for (int nt2 = 0; nt2 < 6; ++nt2) {
        f16x8 bb = *reinterpret_cast<const f16x8*>(&Bs[nt2 * 16 + (lane & 15)][q4 * 8]);
        acc[mb][nt2] = mfma16(a, bb, acc[mb][nt2]);
      }
    }
  }
#pragma unroll
  for (int mb = 0; mb < 2; ++mb)
#pragma unroll
    for (int nt2 = 0; nt2 < 6; ++nt2)
#pragma unroll
      for (int i = 0; i < 4; ++i) {
        int m = m0 + w * 32 + mb * 16 + q4 * 4 + i;
        int n = n0 + nt2 * 16 + (lane & 15);
        xw0[(size_t)m * 576 + n] = acc[mb][nt2][i];
      }
}

// ---------------- K4: pipelined LMU recurrence (bitmap handshake, all-LLC) ----------------
template <int KK>
DI void rec_run(int l, int c, int tid, const f16* __restrict__ gbuf, f16* __restrict__ sbuf,
                const float* __restrict__ xw0, const float* __restrict__ w1f,
                const float* __restrict__ btf, const float* __restrict__ h0,
                const float* __restrict__ m0, unsigned char* done, f16* bflds, f16* smtile) {
  const int lane = tid & 63, w = tid >> 6;
  const int mb = w / 3, nt = w % 3;
  const int nbase = c * 48 + nt * 16;
  const int ncol = nbase + (lane & 15);
  const int q4 = lane >> 4;

  // ---- t=0 state init -> LLC ----
  for (int r = tid; r < 32 * 48; r += 384) {
    int row = r / 48; int col = c * 48 + (r - row * 48);
    float v = (col < 512) ? h0[(size_t)l * 512 + col] : m0[(size_t)l * 256 + col - 512];
    st_h_sc1(sbuf + (size_t)l * LSTRIDE + (size_t)row * 768 + col, (f16)v);
  }

  // ---- weights into registers (+ LDS for the x-tail of KK=40) ----
  const f16* gb = gbuf + ((size_t)l * 768 + ncol) * 1280 + (size_t)q4 * 8;
  constexpr int NREG = (KK > 32) ? 32 : KK;
  f16x8 bf[NREG];
#pragma unroll
  for (int kk = 0; kk < NREG; ++kk) bf[kk] = ldg8(gb + (size_t)kk * 32);
  if (KK == 40) {
#pragma unroll
    for (int kk = 32; kk < 40; ++kk) {
      f16x8 v = ldg8(gb + (size_t)kk * 32);
      *reinterpret_cast<f16x8*>(bflds + ((size_t)(w * 8 + (kk - 32)) * 64 + lane) * 8) = v;
    }
  }
  float w1n = 0.f, btn = 0.f;
  if (KK == 24) {
    if (ncol < 512) w1n = w1f[ncol];
    else btn = btf[ncol - 512];
  }
  drain_vm();       // every thread drains its own init sc1 stores
  __syncthreads();  // + bflds visible
  if (tid == 0) st_b_sc1(done + (size_t)(l * 254) * 16 + c, 1);

  for (int t = 0; t < 253; ++t) {
    // hoist the flag-independent xw0 bias loads (layer 0 only)
    float xadd[4];
    if (KK == 24) {
#pragma unroll
      for (int i = 0; i < 4; ++i) {
        const int brow = mb * 16 + q4 * 4 + i;
        const float* xr = xw0 + ((size_t)brow * 256 + t) * 576;
        float xe = xr[512];
        xadd[i] = (ncol < 512) ? (xr[ncol] + xe * w1n) : (xe * btn);
      }
    }
    if (tid == 0) {
      const int* own = (const int*)(done + (size_t)(l * 254 + t) * 16);
      if (l > 0) poll_two(own, (const int*)(done + (size_t)((l - 1) * 254 + t + 1) * 16));
      else poll_one(own);
    }
    __builtin_amdgcn_s_barrier();
    membar();

    const int arow = mb * 16 + (lane & 15);
    const f16* s0 = sbuf + (size_t)l * LSTRIDE + ((size_t)t * 32 + arow) * 768 + (size_t)q4 * 8;
    f32x4 acc = {0.f, 0.f, 0.f, 0.f};
#pragma unroll
    for (int kk = 0; kk < 24; ++kk) acc = mfma16(ldg8(s0 + (size_t)kk * 32), bf[kk < NREG ? kk : 0], acc);
    if (KK == 40) {
      const f16* s1 = sbuf + (size_t)(l - 1) * LSTRIDE + ((size_t)(t + 1) * 32 + arow) * 768 + (size_t)q4 * 8;
#pragma unroll
      for (int kk = 24; kk < 32; ++kk) acc = mfma16(ldg8(s1 + (size_t)(kk - 24) * 32), bf[kk < NREG ? kk : 0], acc);
#pragma unroll
      for (int kk = 32; kk < 40; ++kk) {
        f16x8 bb = *reinterpret_cast<const f16x8*>(bflds + ((size_t)(w * 8 + (kk - 32)) * 64 + lane) * 8);
        acc = mfma16(ldg8(s1 + (size_t)(kk - 24) * 32), bb, acc);
      }
    }

    // stage output tile in LDS (scattered 2B, conflict-light)
    const int scol = nt * 16 + (lane & 15);
#pragma unroll
    for (int i = 0; i < 4; ++i) {
      float v = acc[i];
      if (KK == 24) v += xadd[i];
      if (ncol < 512) v = tanh_fast(v);
      smtile[(mb * 16 + q4 * 4 + i) * 48 + scol] = (f16)v;
    }
    __syncthreads();
    {  // coalesced export: 384 threads x 8B (96B contiguous per row)
      int row = tid / 12; int c4 = (tid - row * 12) * 4;
      f16x4 v4 = *reinterpret_cast<const f16x4*>(smtile + row * 48 + c4);
      f16* dst = sbuf + (size_t)l * LSTRIDE + ((size_t)(t + 1) * 32 + row) * 768 + c * 48 + c4;
      st8_sc1(dst, v4);  // per-thread vmcnt(0)
    }
    __builtin_amdgcn_s_barrier();  // all threads' state stores are at LLC
    if (tid == 0) st_b_sc1(done + (size_t)(l * 254 + t + 1) * 16 + c, 1);  // fire-and-forget
  }
}

__global__ __launch_bounds__(384, 2) void k_rec(const f16* __restrict__ gbuf, f16* __restrict__ sbuf,
    const float* __restrict__ xw0, const float* __restrict__ w1f,
    const float* __restrict__ btf, const float* __restrict__ h0,
    const float* __restrict__ m0, unsigned char* __restrict__ done) {
  __shared__ f16 bflds[6 * 8 * 64 * 8];
  __shared__ f16 smtile[32 * 48];
  const int l = blockIdx.x & 7;  // layer -> XCD locality heuristic (perf only)
  if (l >= 5) return;
  const int c = blockIdx.x >> 3;
  if (l == 0)
    rec_run<24>(0, c, threadIdx.x, gbuf, sbuf, xw0, w1f, btf, h0, m0, done, bflds, smtile);
  else
    rec_run<40>(l, c, threadIdx.x, gbuf, sbuf, xw0, w1f, btf, h0, m0, done, bflds, smtile);
}

// ---------------- K5: output projection ----------------
__global__ __launch_bounds__(256) void k_out(const f16* __restrict__ sbuf4,
    const f16* __restrict__ outw, const float* __restrict__ outb, float* __restrict__ out) {
  const int bid = blockIdx.x; const int b = bid >> 2; const int tp0 = (bid & 3) * 64;
  const int tid = threadIdx.x, lane = tid & 63, w = tid >> 6, q4 = lane >> 4;
  f32x4 acc[3];
#pragma unroll
  for (int i = 0; i < 3; ++i) acc[i] = (f32x4){0.f, 0.f, 0.f, 0.f};
  int tq = tp0 + w * 16 + (lane & 15) + 1;
  const int tau = tq > 253 ? 253 : tq;
  const f16* arow = sbuf4 + ((size_t)tau * 32 + b) * 768 + (size_t)q4 * 8;
#pragma unroll
  for (int kk = 0; kk < 16; ++kk) {
    f16x8 a = ldg8(arow + (size_t)kk * 32);
#pragma unroll
    for (int nt2 = 0; nt2 < 3; ++nt2) {
      f16x8 bb = ldg8(outw + (size_t)(nt2 * 16 + (lane & 15)) * 512 + kk * 32 + q4 * 8);
      acc[nt2] = mfma16(a, bb, acc[nt2]);
    }
  }
#pragma unroll
  for (int nt2 = 0; nt2 < 3; ++nt2) {
    int cc = nt2 * 16 + (lane & 15);
    if (cc < 41) {
      float ob = outb[cc];
#pragma unroll
      for (int i = 0; i < 4; ++i) {
        int tp = tp0 + w * 16 + q4 * 4 + i;
        if (tp < 253) out[((size_t)b * 253 + tp) * 41 + cc] = acc[nt2][i] + ob;
      }
    }
  }
}

extern "C" void kernel_launch(void* const* d_in, const int* in_sizes, int n_in,
                              void* d_out, int out_size, void* d_ws, size_t ws_size,
                              hipStream_t stream) {
  const float* x      = (const float*)d_in[0];
  const int*   dayIdx = (const int*)d_in[1];
  const float* day_W  = (const float*)d_in[2];
  const float* day_b  = (const float*)d_in[3];
  const float* e_x0   = (const float*)d_in[4];
  const float* W_x0   = (const float*)d_in[5];
  const float* e_xr   = (const float*)d_in[6];
  const float* W_xr   = (const float*)d_in[7];
  const float* e_h    = (const float*)d_in[8];
  const float* e_m    = (const float*)d_in[9];
  const float* W_h    = (const float*)d_in[10];
  const float* W_m    = (const float*)d_in[11];
  const float* h0     = (const float*)d_in[12];
  const float* m0     = (const float*)d_in[13];
  const float* out_W  = (const float*)d_in[14];
  const float* out_b  = (const float*)d_in[15];
  float* outp = (float*)d_out;

  char* w = (char*)d_ws;
  size_t o = 0;
  auto al = [&](size_t n) { void* p = w + o; o = (o + n + 255) & ~(size_t)255; return p; };

  int*   flags = (int*)  al(32768);   // [0,20320): bitmap; ints 6144+: setup barrier
  f16*   gbuf  = (f16*)  al((size_t)5 * 768 * 1280 * 2);
  f16*   outw  = (f16*)  al((size_t)48 * 512 * 2);
  float* xw0   = (float*)al((size_t)8192 * 576 * 4);
  float* w1f   = (float*)al((size_t)5 * 512 * 4);
  float* btf   = (float*)al(256 * 4);

  // overlay: setup temporaries (X, AWt, dayWt, wxcat, h1) are dead before
  // k_rec writes sbuf — alias them over the sbuf region.
  const size_t XB    = ((size_t)17 * N2 * 8 + 255) & ~(size_t)255;
  const size_t AWTB  = ((size_t)5 * 512 * 256 * 4 + 255) & ~(size_t)255;
  const size_t DAYB  = ((size_t)24 * 512 * 512 * 2 + 255) & ~(size_t)255;
  const size_t WXB   = ((size_t)576 * 7168 * 2 + 255) & ~(size_t)255;
  const size_t H1B   = ((size_t)32 * 1024 * 512 * 2 + 255) & ~(size_t)255;
  const size_t SBUFB = (size_t)5 * LSTRIDE * 2;
  size_t ovb = XB + AWTB + DAYB + WXB + H1B;
  if (SBUFB > ovb) ovb = SBUFB;
  char* ov = (char*)al(ovb);
  double* X     = (double*)ov;
  float*  AWt   = (float*)(ov + XB);
  f16*    dayWt = (f16*)(ov + XB + AWTB);
  f16*    wxcat = (f16*)(ov + XB + AWTB + DAYB);
  f16*    h1    = (f16*)(ov + XB + AWTB + DAYB + WXB);
  f16*    sbuf  = (f16*)ov;

  if (o > ws_size) return;  // workspace too small -> fail loudly
  (void)in_sizes; (void)n_in; (void)out_size;

  hipMemsetAsync(flags, 0, 32768, stream);
  k_setup<<<128, 256, 0, stream>>>(day_W, e_x0, W_x0, e_xr, W_xr, e_h, e_m, W_h, W_m,
                                   out_W, X, w1f, AWt, btf, gbuf, wxcat, outw, dayWt,
                                   flags + 6144);
  k_day<<<1024, 256, 0, stream>>>(x, dayIdx, day_b, dayWt, h1);
  k_xw0<<<384, 256, 0, stream>>>(h1, wxcat, xw0);
  k_rec<<<128, 384, 0, stream>>>(gbuf, sbuf, xw0, w1f, btf, h0, m0, (unsigned char*)flags);
  k_out<<<128, 256, 0, stream>>>(sbuf + (size_t)4 * LSTRIDE, outw, out_b, outp);
}